// Round 1
// baseline (327.804 us; speedup 1.0000x reference)
//
#include <hip/hip_runtime.h>

// AttentionGate: out[b,cf,v] = x[b,cf,v] * sigmoid(Wpsi · relu(Wg·g[b,:,v] + Wx·x[b,:,v]))
// B=2, CF=CG=64, CI=32, SPAT=64^3. fp32.
//
// R3: occupancy play. R2 (2 voxels/thread) capped the machine at 1024 blocks =
// 16 waves/CU (50%); counters showed VALUBusy 31% AND hbm at 48%-of-achievable —
// latency-bound underlap, neither pipe saturated. Switch to 1 voxel/thread:
// 2048 blocks -> 8 blocks/CU -> 32 waves/CU (100% cap). acc shrinks 64->32 VGPRs
// so __launch_bounds__(256,8) (<=64 VGPR) holds without spills. unroll 4 keeps
// 8 x 256B loads in flight per wave; epilogue unroll 8. g/out stay nontemporal
// (read-once/write-once); x loads stay cached for the epilogue re-read.

#define SPAT 262144        // 64*64*64 voxels per (b,c) plane, 2^18
#define NVOX 524288        // B * SPAT
#define CIN  64
#define COUT 32

__global__ __launch_bounds__(256) void transpose_w(const float* __restrict__ Wg,
                                                   const float* __restrict__ Wx,
                                                   float* __restrict__ Wcat) {
    int idx = blockIdx.x * 256 + threadIdx.x;   // 0..4095
    int c = idx >> 6;
    int o = idx & 63;
    float v = (o < 32) ? Wg[o * CIN + c] : Wx[(o - 32) * CIN + c];
    Wcat[c * 64 + o] = v;
}

__global__ __launch_bounds__(256, 8) void gate_main(const float* __restrict__ x,
                                                    const float* __restrict__ g,
                                                    const float* __restrict__ Wcat,
                                                    const float* __restrict__ Wpsi,
                                                    float* __restrict__ out) {
    int p = blockIdx.x * 256 + threadIdx.x;     // voxel index 0..524287
    int b = p >> 18;                            // SPAT = 2^18
    int s = p & (SPAT - 1);

    const float* __restrict__ xp = x + (size_t)b * CIN * SPAT + s;
    const float* __restrict__ gp = g + (size_t)b * CIN * SPAT + s;

    float acc[COUT];
#pragma unroll
    for (int o = 0; o < COUT; ++o) acc[o] = 0.0f;

#pragma unroll 4
    for (int c = 0; c < CIN; ++c) {
        float gc = __builtin_nontemporal_load(gp + (size_t)c * SPAT);  // g read once
        float xc = xp[(size_t)c * SPAT];                               // x re-read in epilogue
        const float* w = Wcat + c * 64;         // wave-uniform -> scalar loads
#pragma unroll
        for (int o = 0; o < COUT; ++o) {
            acc[o] = fmaf(w[o], gc, fmaf(w[32 + o], xc, acc[o]));
        }
    }

    float ps = 0.0f;
#pragma unroll
    for (int o = 0; o < COUT; ++o) {
        ps = fmaf(Wpsi[o], fmaxf(acc[o], 0.0f), ps);
    }
    float psi = 1.0f / (1.0f + __expf(-ps));

    float* __restrict__ op = out + (size_t)b * CIN * SPAT + s;
#pragma unroll 8
    for (int c = 0; c < CIN; ++c) {
        float xv = xp[(size_t)c * SPAT];        // L2/L3-warm re-read
        __builtin_nontemporal_store(xv * psi, op + (size_t)c * SPAT);  // write-once
    }
}

extern "C" void kernel_launch(void* const* d_in, const int* in_sizes, int n_in,
                              void* d_out, int out_size, void* d_ws, size_t ws_size,
                              hipStream_t stream) {
    const float* x    = (const float*)d_in[0];
    const float* g    = (const float*)d_in[1];
    const float* Wg   = (const float*)d_in[2];
    const float* Wx   = (const float*)d_in[3];
    const float* Wpsi = (const float*)d_in[4];
    float* out  = (float*)d_out;
    float* Wcat = (float*)d_ws;                 // 64*64 floats = 16 KB scratch

    transpose_w<<<16, 256, 0, stream>>>(Wg, Wx, Wcat);
    gate_main<<<NVOX / 256, 256, 0, stream>>>(x, g, Wcat, Wpsi, out);
}